// Round 7
// baseline (357.043 us; speedup 1.0000x reference)
//
#include <hip/hip_runtime.h>
#include <math.h>

#define ROWS 65536        // 4*128*128
#define KDD 192

typedef __attribute__((ext_vector_type(8))) short bfrag;   // 8 bf16
typedef __attribute__((ext_vector_type(4))) float facc;    // 4 fp32

__device__ inline unsigned short bf16r(float x) {
  union { float f; unsigned u; } v; v.f = x;
  unsigned r = v.u + 0x7fffu + ((v.u >> 16) & 1u);
  return (unsigned short)(r >> 16);
}
__device__ inline float bf2f(unsigned short h) {
  union { unsigned u; float f; } v; v.u = ((unsigned)h) << 16; return v.f;
}
__device__ inline float gelu_f(float x) {
  return x * 0.5f * (1.f + erff(x * 0.70710678f));
}

// ---------------- LayerNorm over last dim (128), bf16 output ----------------
__global__ __launch_bounds__(128) void k_ln(const float* __restrict__ x,
                                            const float* __restrict__ g,
                                            const float* __restrict__ bb,
                                            unsigned short* __restrict__ y) {
  int row = blockIdx.x;
  int t = threadIdx.x;
  float v = x[(size_t)row * 128 + t];
  float s = v, s2 = v * v;
  for (int off = 32; off > 0; off >>= 1) {
    s += __shfl_down(s, off, 64);
    s2 += __shfl_down(s2, off, 64);
  }
  __shared__ float ps[2], ps2[2];
  int wid = t >> 6, lane = t & 63;
  if (lane == 0) { ps[wid] = s; ps2[wid] = s2; }
  __syncthreads();
  float S = ps[0] + ps[1], S2 = ps2[0] + ps2[1];
  float mean = S * (1.f / 128.f);
  float var = S2 * (1.f / 128.f) - mean * mean;
  float r = rsqrtf(var + 1e-5f);
  y[(size_t)row * 128 + t] = bf16r((v - mean) * r * g[t] + bb[t]);
}

// ---------------- means of un(bf16) over ny (blk<512) / nx (else) ----------------
__global__ __launch_bounds__(128) void k_means(const unsigned short* __restrict__ un,
                                               float* __restrict__ mx, float* __restrict__ my) {
  int blk = blockIdx.x;
  int c = threadIdx.x;
  if (blk < 512) {
    const unsigned short* p = un + (size_t)blk * 16384 + c;
    float s = 0;
    for (int j = 0; j < 128; j++) s += bf2f(p[(size_t)j * 128]);
    mx[(size_t)blk * 128 + c] = s * (1.f / 128.f);
  } else {
    int bj = blk - 512;
    int b = bj >> 7, j = bj & 127;
    const unsigned short* p = un + (size_t)b * 2097152 + (size_t)j * 128 + c;
    float s = 0;
    for (int i = 0; i < 128; i++) s += bf2f(p[(size_t)i * 16384]);
    my[(size_t)bj * 128 + c] = s * (1.f / 128.f);
  }
}

// -------- weight prep: bf16 transposes + colsum + the two Wc=Win@p_Win gemms --------
__global__ __launch_bounds__(256) void k_wprep(const float* __restrict__ Wv,
                                               const float* __restrict__ Wo1,
                                               const float* __restrict__ Wo2,
                                               const float* __restrict__ Win,
                                               const float* __restrict__ pxWin,
                                               const float* __restrict__ pyWin,
                                               unsigned short* __restrict__ WvT,
                                               unsigned short* __restrict__ Wo1T,
                                               unsigned short* __restrict__ Wo2T,
                                               float* __restrict__ Wcx,
                                               float* __restrict__ Wcy,
                                               float* __restrict__ scol) {
  __shared__ float As[16][64];
  __shared__ float Bs[16][64];
  int blk = blockIdx.x, t = threadIdx.x;
  if (blk < 256) {
    int idx = blk * 256 + t;            // 65536: WvT[hc][d] = Wv[d][hc]
    int c = idx >> 7, r = idx & 127;
    WvT[(size_t)c * 128 + r] = bf16r(Wv[(size_t)r * 512 + c]);
  } else if (blk < 512) {
    int idx = (blk - 256) * 256 + t;    // 65536: Wo1T[n][k] = Wo1[k][n]
    int n = idx >> 9, k = idx & 511;
    Wo1T[(size_t)n * 512 + k] = bf16r(Wo1[(size_t)k * 128 + n]);
  } else if (blk < 576) {
    int idx = (blk - 512) * 256 + t;    // 16384: Wo2T[n][k] = Wo2[k][n]
    int n = idx >> 7, k = idx & 127;
    Wo2T[n * 128 + k] = bf16r(Wo2[k * 128 + n]);
  } else if (blk == 576) {
    if (t < 128) {
      float a = 0;
      for (int k = 0; k < 512; k++) a += bf2f(bf16r(Wo1[k * 128 + t]));
      scol[t] = a;
    }
  } else {
    // Wc gemms: 8 blocks, 64x64 tiles, K=128
    int g = blk - 577;
    int sel = g >> 2, t2 = g & 3;
    const float* A = Win;
    const float* Bm = sel ? pyWin : pxWin;
    float* C = sel ? Wcy : Wcx;
    int n0 = (t2 & 1) * 64, m0 = (t2 >> 1) * 64;
    int tx = t & 15, ty = t >> 4;
    float acc[4][4] = {};
    int la_m = t >> 2, la_k = (t & 3) * 4;
    int lb_k = t >> 4, lb_n = (t & 15) * 4;
    for (int k0 = 0; k0 < 128; k0 += 16) {
      float4 a4 = *(const float4*)(A + (size_t)(m0 + la_m) * 128 + k0 + la_k);
      As[la_k + 0][la_m] = a4.x; As[la_k + 1][la_m] = a4.y;
      As[la_k + 2][la_m] = a4.z; As[la_k + 3][la_m] = a4.w;
      float4 b4 = *(const float4*)(Bm + (size_t)(k0 + lb_k) * 128 + n0 + lb_n);
      *(float4*)&Bs[lb_k][lb_n] = b4;
      __syncthreads();
#pragma unroll
      for (int kk = 0; kk < 16; kk++) {
        float4 av = *(const float4*)&As[kk][ty * 4];
        float4 bv = *(const float4*)&Bs[kk][tx * 4];
        float a[4] = {av.x, av.y, av.z, av.w};
        float b[4] = {bv.x, bv.y, bv.z, bv.w};
#pragma unroll
        for (int i = 0; i < 4; i++)
#pragma unroll
          for (int j = 0; j < 4; j++) acc[i][j] += a[i] * b[j];
      }
      __syncthreads();
    }
#pragma unroll
    for (int i = 0; i < 4; i++) {
      float4 o;
      o.x = acc[i][0]; o.y = acc[i][1]; o.z = acc[i][2]; o.w = acc[i][3];
      *(float4*)(C + (size_t)(m0 + ty * 4 + i) * 128 + n0 + tx * 4) = o;
    }
  }
}

// ---------------- fp32 GEMM, z-batched (qk projections) ----------------
__global__ __launch_bounds__(256) void k_gemmz(const float* __restrict__ A0,
                                               const float* __restrict__ B0,
                                               float* __restrict__ C0,
                                               const float* __restrict__ A1,
                                               const float* __restrict__ B1,
                                               float* __restrict__ C1,
                                               int K, int lda, int ldb, int ldc) {
  const float* A = blockIdx.z ? A1 : A0;
  const float* Bm = blockIdx.z ? B1 : B0;
  float* C = blockIdx.z ? C1 : C0;
  __shared__ float As[16][64];
  __shared__ float Bs[16][64];
  int tid = threadIdx.x;
  int n0 = blockIdx.x * 64, m0 = blockIdx.y * 64;
  int tx = tid & 15, ty = tid >> 4;
  float acc[4][4] = {};
  int la_m = tid >> 2, la_k = (tid & 3) * 4;
  int lb_k = tid >> 4, lb_n = (tid & 15) * 4;
  for (int k0 = 0; k0 < K; k0 += 16) {
    float4 a4 = *(const float4*)(A + (size_t)(m0 + la_m) * lda + k0 + la_k);
    As[la_k + 0][la_m] = a4.x; As[la_k + 1][la_m] = a4.y;
    As[la_k + 2][la_m] = a4.z; As[la_k + 3][la_m] = a4.w;
    float4 b4 = *(const float4*)(Bm + (size_t)(k0 + lb_k) * ldb + n0 + lb_n);
    *(float4*)&Bs[lb_k][lb_n] = b4;
    __syncthreads();
#pragma unroll
    for (int kk = 0; kk < 16; kk++) {
      float4 av = *(const float4*)&As[kk][ty * 4];
      float4 bv = *(const float4*)&Bs[kk][tx * 4];
      float a[4] = {av.x, av.y, av.z, av.w};
      float b[4] = {bv.x, bv.y, bv.z, bv.w};
#pragma unroll
      for (int i = 0; i < 4; i++)
#pragma unroll
        for (int j = 0; j < 4; j++) acc[i][j] += a[i] * b[j];
    }
    __syncthreads();
  }
#pragma unroll
  for (int i = 0; i < 4; i++) {
    float4 o;
    o.x = acc[i][0]; o.y = acc[i][1]; o.z = acc[i][2]; o.w = acc[i][3];
    *(float4*)(C + (size_t)(m0 + ty * 4 + i) * ldc + n0 + tx * 4) = o;
  }
}

// ---------------- pooling MLP, y-batched ----------------
__global__ __launch_bounds__(128) void k_pool2(const float* __restrict__ in0, const float* __restrict__ in1,
                                               const float* __restrict__ Wc0, const float* __restrict__ Wc1,
                                               const float* __restrict__ g0, const float* __restrict__ g1,
                                               const float* __restrict__ bb0, const float* __restrict__ bb1,
                                               const float* __restrict__ W10, const float* __restrict__ W11,
                                               const float* __restrict__ b10, const float* __restrict__ b11,
                                               const float* __restrict__ W20, const float* __restrict__ W21,
                                               const float* __restrict__ b20, const float* __restrict__ b21,
                                               float* __restrict__ o0, float* __restrict__ o1) {
  int sel = blockIdx.y;
  const float* in = sel ? in1 : in0;  const float* Wc = sel ? Wc1 : Wc0;
  const float* g = sel ? g1 : g0;     const float* bb = sel ? bb1 : bb0;
  const float* W1 = sel ? W11 : W10;  const float* b1 = sel ? b11 : b10;
  const float* W2 = sel ? W21 : W20;  const float* b2 = sel ? b21 : b20;
  float* out = sel ? o1 : o0;
  int row = blockIdx.x;
  int t = threadIdx.x;
  __shared__ float xin[128], h1[128], h3[128];
  __shared__ float ps[2], ps2[2];
  xin[t] = in[(size_t)row * 128 + t];
  __syncthreads();
  float a = 0;
  for (int k = 0; k < 128; k++) a += xin[k] * Wc[k * 128 + t];
  float s = a, s2 = a * a;
  for (int off = 32; off > 0; off >>= 1) {
    s += __shfl_down(s, off, 64);
    s2 += __shfl_down(s2, off, 64);
  }
  if ((t & 63) == 0) { ps[t >> 6] = s; ps2[t >> 6] = s2; }
  __syncthreads();
  float S = ps[0] + ps[1], S2 = ps2[0] + ps2[1];
  float mean = S * (1.f / 128.f);
  float var = S2 * (1.f / 128.f) - mean * mean;
  float r = rsqrtf(var + 1e-5f);
  h1[t] = (a - mean) * r * g[t] + bb[t];
  __syncthreads();
  float u1 = b1[t], u2 = b1[t + 128];
  for (int k = 0; k < 128; k++) {
    float hv = h1[k];
    u1 += hv * W1[k * 256 + t];
    u2 += hv * W1[k * 256 + t + 128];
  }
  h3[t] = gelu_f(u1) * u2;
  __syncthreads();
  if (t < 64) {
    float o = b2[t];
    for (int k = 0; k < 128; k++) o += h3[k] * W2[k * 64 + t];
    out[(size_t)row * 64 + t] = o;
  }
}

// -------- Q@K^T per (b,h) with inline rotary, bf16 out, z: 0-31 x / 32-63 y --------
__global__ __launch_bounds__(256) void k_qkt3(const float* __restrict__ qkx,
                                              const float* __restrict__ qky,
                                              const float* __restrict__ pos_x,
                                              const float* __restrict__ pos_y,
                                              unsigned short* __restrict__ Cx,
                                              unsigned short* __restrict__ Cy) {
  int z = blockIdx.z;
  int bh = z & 31;
  int b = bh >> 3, h = bh & 7;
  const float* qk = (z < 32) ? qkx : qky;
  const float* pos = (z < 32) ? pos_x : pos_y;
  unsigned short* Cb = ((z < 32) ? Cx : Cy) + (size_t)bh * 16384;
  __shared__ float As[16][64];
  __shared__ float Bs[16][64];
  int tid = threadIdx.x;
  int i0 = blockIdx.y * 64, j0 = blockIdx.x * 64;
  int tx = tid & 15, ty = tid >> 4;
  float acc[4][4] = {};
  int l_m = tid >> 2, l_k = (tid & 3) * 4;
  const float LOG1E4 = 9.21034037f;  // ln(10000)
  for (int k0 = 0; k0 < KDD; k0 += 16) {
    int d = k0 + l_k;                 // 4-aligned; block of 4 entirely <96 or >=96
    int fi = d % 96;
    int prt = d < 96 ? d + 96 : d - 96;
    float sgn = d < 96 ? -1.f : 1.f;
    // frequencies for the 4 d's
    float cs[4], sn[4];
    {
      int nA = i0 + l_m;
      float p64 = pos[nA] * 64.f;
#pragma unroll
      for (int q = 0; q < 4; q++) {
        float inv = expf(-LOG1E4 * ((float)(fi + q) * (1.f / 96.f)));
        float f = p64 * inv;
        cs[q] = cosf(f); sn[q] = sinf(f);
      }
      const float* base = qk + (size_t)(b * 128 + nA) * 3072 + h * 192;
      float4 tq = *(const float4*)(base + d);
      float4 tp = *(const float4*)(base + prt);
      As[l_k + 0][l_m] = tq.x * cs[0] + sgn * tp.x * sn[0];
      As[l_k + 1][l_m] = tq.y * cs[1] + sgn * tp.y * sn[1];
      As[l_k + 2][l_m] = tq.z * cs[2] + sgn * tp.z * sn[2];
      As[l_k + 3][l_m] = tq.w * cs[3] + sgn * tp.w * sn[3];
    }
    {
      int nB = j0 + l_m;
      float p64 = pos[nB] * 64.f;
#pragma unroll
      for (int q = 0; q < 4; q++) {
        float inv = expf(-LOG1E4 * ((float)(fi + q) * (1.f / 96.f)));
        float f = p64 * inv;
        cs[q] = cosf(f); sn[q] = sinf(f);
      }
      const float* base = qk + (size_t)(b * 128 + nB) * 3072 + 1536 + h * 192;
      float4 tq = *(const float4*)(base + d);
      float4 tp = *(const float4*)(base + prt);
      Bs[l_k + 0][l_m] = tq.x * cs[0] + sgn * tp.x * sn[0];
      Bs[l_k + 1][l_m] = tq.y * cs[1] + sgn * tp.y * sn[1];
      Bs[l_k + 2][l_m] = tq.z * cs[2] + sgn * tp.z * sn[2];
      Bs[l_k + 3][l_m] = tq.w * cs[3] + sgn * tp.w * sn[3];
    }
    __syncthreads();
#pragma unroll
    for (int kk = 0; kk < 16; kk++) {
      float4 av = *(const float4*)&As[kk][ty * 4];
      float4 bv = *(const float4*)&Bs[kk][tx * 4];
      float a[4] = {av.x, av.y, av.z, av.w};
      float bb[4] = {bv.x, bv.y, bv.z, bv.w};
#pragma unroll
      for (int i = 0; i < 4; i++)
#pragma unroll
        for (int j = 0; j < 4; j++) acc[i][j] += a[i] * bb[j];
    }
    __syncthreads();
  }
#pragma unroll
  for (int i = 0; i < 4; i++) {
    unsigned h0 = bf16r(acc[i][0]), h1 = bf16r(acc[i][1]);
    unsigned h2 = bf16r(acc[i][2]), h3 = bf16r(acc[i][3]);
    uint2 pk;
    pk.x = h0 | (h1 << 16);
    pk.y = h2 | (h3 << 16);
    *(uint2*)(Cb + (size_t)(i0 + ty * 4 + i) * 128 + j0 + tx * 4) = pk;
  }
}

// ==== xor-swizzled LDS: phys = row*128 + ((c8 ^ (row&15))<<3) + (col&7), c8=col>>3 ====

// ---- vT[hc][(b,j,m)] = (un@Wv)^T ; one un-tile read, 4 WvT strips looped ----
__global__ __launch_bounds__(256) void k_vt(const unsigned short* __restrict__ WvT,
                                            const unsigned short* __restrict__ un,
                                            unsigned short* __restrict__ vT) {
  int nt = blockIdx.x;   // bjm tile (0..511)
  __shared__ __align__(16) unsigned short As[16384];
  __shared__ __align__(16) unsigned short Bs[16384];
  int tid = threadIdx.x;
  int w = tid >> 6, lane = tid & 63, quad = lane >> 4, l16 = lane & 15;
  {
    int r = tid >> 1, half = tid & 1;
    const unsigned short* sbp = un + (size_t)(nt * 128 + r) * 128 + half * 64;
#pragma unroll
    for (int q = 0; q < 8; q++) {
      int c8 = half * 8 + q;
      *(uint4*)&Bs[r * 128 + ((c8 ^ (r & 15)) << 3)] = *(const uint4*)(sbp + q * 8);
    }
  }
  facc zf = {0.f, 0.f, 0.f, 0.f};
  for (int mt = 0; mt < 4; mt++) {
    if (mt) __syncthreads();
    {
      int r = tid >> 1, half = tid & 1;
      const unsigned short* sa = WvT + (size_t)(mt * 128 + r) * 128 + half * 64;
#pragma unroll
      for (int q = 0; q < 8; q++) {
        int c8 = half * 8 + q;
        *(uint4*)&As[r * 128 + ((c8 ^ (r & 15)) << 3)] = *(const uint4*)(sa + q * 8);
      }
    }
    __syncthreads();
    facc acc[2][8];
#pragma unroll
    for (int a = 0; a < 2; a++)
#pragma unroll
      for (int bq = 0; bq < 8; bq++) acc[a][bq] = zf;
#pragma unroll
    for (int k0 = 0; k0 < 4; k0++) {
      bfrag av[2];
#pragma unroll
      for (int it = 0; it < 2; it++) {
        int row = (w + it * 4) * 16 + l16;
        av[it] = *(const bfrag*)&As[row * 128 + (((k0 * 4 + quad) ^ l16) << 3)];
      }
#pragma unroll
      for (int nt8 = 0; nt8 < 8; nt8++) {
        int row = nt8 * 16 + l16;
        bfrag bv = *(const bfrag*)&Bs[row * 128 + (((k0 * 4 + quad) ^ l16) << 3)];
        acc[0][nt8] = __builtin_amdgcn_mfma_f32_16x16x32_bf16(av[0], bv, acc[0][nt8], 0, 0, 0);
        acc[1][nt8] = __builtin_amdgcn_mfma_f32_16x16x32_bf16(av[1], bv, acc[1][nt8], 0, 0, 0);
      }
    }
    __syncthreads();
#pragma unroll
    for (int it = 0; it < 2; it++)
#pragma unroll
      for (int nt8 = 0; nt8 < 8; nt8++)
#pragma unroll
        for (int rr = 0; rr < 4; rr++) {
          int row = (w + it * 4) * 16 + quad * 4 + rr;
          int col = nt8 * 16 + l16;
          As[row * 128 + (((col >> 3) ^ (row & 15)) << 3) + (col & 7)] = bf16r(acc[it][nt8][rr]);
        }
    __syncthreads();
    {
      int r = tid >> 1, half = tid & 1;
      unsigned short* dst = vT + (size_t)(mt * 128 + r) * 65536 + (size_t)nt * 128 + half * 64;
#pragma unroll
      for (int q = 0; q < 8; q++) {
        int c8 = half * 8 + q;
        *(uint4*)(dst + q * 8) = *(const uint4*)&As[r * 128 + ((c8 ^ (r & 15)) << 3)];
      }
    }
  }
}

// ---- fused x/y attend, one (bh,c) per block: tt'[bh][c][i][l] = kx @ (Vc @ ky^T) ----
__global__ __launch_bounds__(256) void k_fuse12(const unsigned short* __restrict__ kxall,
                                                const unsigned short* __restrict__ kyall,
                                                const unsigned short* __restrict__ vT,
                                                unsigned short* __restrict__ ttp,
                                                float* __restrict__ sb,
                                                float* __restrict__ s2b) {
  int blk = blockIdx.x;            // 2048 = bh*64 + c
  int bh = blk >> 6, c = blk & 63;
  int b = bh >> 3, h = bh & 7;
  __shared__ __align__(16) unsigned short Ky[16384];   // ky, then S^T
  __shared__ __align__(16) unsigned short Vs[16384];   // Vc, then D
  __shared__ float sL[128], s2L[128];
  int tid = threadIdx.x;
  int w = tid >> 6, lane = tid & 63, quad = lane >> 4, l16 = lane & 15;
  if (tid < 128) { sL[tid] = 0.f; s2L[tid] = 0.f; }
  {
    int r = tid >> 1, half = tid & 1;
    const unsigned short* s = kyall + (size_t)bh * 16384 + (size_t)r * 128 + half * 64;
    const unsigned short* sv = vT + (size_t)(h * 64 + c) * 65536 + (size_t)b * 16384 +
                               (size_t)r * 128 + half * 64;
#pragma unroll
    for (int q = 0; q < 8; q++) {
      int c8 = half * 8 + q;
      int ph = ((c8 ^ (r & 15)) << 3);
      *(uint4*)&Ky[r * 128 + ph] = *(const uint4*)(s + q * 8);
      *(uint4*)&Vs[r * 128 + ph] = *(const uint4*)(sv + q * 8);
    }
  }
  // kx fragments in registers
  uint4 axf[2][4];
#pragma unroll
  for (int it = 0; it < 2; it++) {
    int i = (w + it * 4) * 16 + l16;
#pragma unroll
    for (int k0 = 0; k0 < 4; k0++)
      axf[it][k0] = *(const uint4*)(kxall + (size_t)bh * 16384 + (size_t)i * 128 + k0 * 32 + quad * 8);
  }
  __syncthreads();
  facc zf = {0.f, 0.f, 0.f, 0.f};
  // stage 1: S[j][l] = sum_m Vc[j][m] * ky[l][m]
  facc a1[2][8];
#pragma unroll
  for (int a = 0; a < 2; a++)
#pragma unroll
    for (int bq = 0; bq < 8; bq++) a1[a][bq] = zf;
#pragma unroll
  for (int k0 = 0; k0 < 4; k0++) {
    bfrag av[2];
#pragma unroll
    for (int it = 0; it < 2; it++) {
      int row = (w + it * 4) * 16 + l16;
      av[it] = *(const bfrag*)&Vs[row * 128 + (((k0 * 4 + quad) ^ l16) << 3)];
    }
#pragma unroll
    for (int lt = 0; lt < 8; lt++) {
      int row = lt * 16 + l16;
      bfrag bv = *(const bfrag*)&Ky[row * 128 + (((k0 * 4 + quad) ^ l16) << 3)];
      a1[0][lt] = __builtin_amdgcn_mfma_f32_16x16x32_bf16(av[0], bv, a1[0][lt], 0, 0, 0);
      a1[1][lt] = __builtin_amdgcn_mfma_f32_16x16x32_bf16(av[1], bv, a1[1][lt], 0, 0, 0);
    }
  }
  __syncthreads();
  // S^T[l][j] overwrites Ky
#pragma unroll
  for (int it = 0; it < 2; it++)
#pragma unroll
    for (int lt = 0; lt < 8; lt++)
#pragma unroll
      for (int rr = 0; rr < 4; rr++) {
        int j = (w + it * 4) * 16 + quad * 4 + rr;
        int l = lt * 16 + l16;
        Ky[l * 128 + (((j >> 3) ^ (l & 15)) << 3) + (j & 7)] = bf16r(a1[it][lt][rr]);
      }
  __syncthreads();
  // stage 2: D[i][l] = sum_j kx[i][j] * St[l][j]
  facc a2[2][8];
#pragma unroll
  for (int a = 0; a < 2; a++)
#pragma unroll
    for (int bq = 0; bq < 8; bq++) a2[a][bq] = zf;
#pragma unroll
  for (int k0 = 0; k0 < 4; k0++) {
    bfrag av0 = *(const bfrag*)&axf[0][k0];
    bfrag av1 = *(const bfrag*)&axf[1][k0];
#pragma unroll
    for (int lt = 0; lt < 8; lt++) {
      int row = lt * 16 + l16;
      bfrag bv = *(const bfrag*)&Ky[row * 128 + (((k0 * 4 + quad) ^ l16) << 3)];
      a2[0][lt] = __builtin_amdgcn_mfma_f32_16x16x32_bf16(av0, bv, a2[0][lt], 0, 0, 0);
      a2[1][lt] = __builtin_amdgcn_mfma_f32_16x16x32_bf16(av1, bv, a2[1][lt], 0, 0, 0);
    }
  }
  // D into Vs (Vs reads all completed before the St-write barrier)
#pragma unroll
  for (int it = 0; it < 2; it++)
#pragma unroll
    for (int lt = 0; lt < 8; lt++)
#pragma unroll
      for (int rr = 0; rr < 4; rr++) {
        int i = (w + it * 4) * 16 + quad * 4 + rr;
        int l = lt * 16 + l16;
        Vs[i * 128 + (((l >> 3) ^ (i & 15)) << 3) + (l & 7)] = bf16r(a2[it][lt][rr]);
      }
  __syncthreads();
  // coalesced store + stats
  {
    int r = tid >> 1, half = tid & 1;
    float s = 0.f, s2 = 0.f;
    unsigned short* dst = ttp + ((size_t)(bh * 64 + c) * 128 + r) * 128 + half * 64;
#pragma unroll
    for (int q = 0; q < 8; q++) {
      int c8 = half * 8 + q;
      uint4 v = *(const uint4*)&Vs[r * 128 + ((c8 ^ (r & 15)) << 3)];
      *(uint4*)(dst + q * 8) = v;
      unsigned short* pv = (unsigned short*)&v;
#pragma unroll
      for (int e = 0; e < 8; e++) { float f = bf2f(pv[e]); s += f; s2 += f * f; }
    }
    atomicAdd(&sL[r], s);
    atomicAdd(&s2L[r], s2);
  }
  __syncthreads();
  if (tid < 128) {
    atomicAdd(&sb[b * 128 + tid], sL[tid]);
    atomicAdd(&s2b[b * 128 + tid], s2L[tid]);
  }
}

// ---- tail per (b,i): out[l][:] = gelu(instnorm(tt)[l,:] @ Wo1) @ Wo2 ----
__global__ __launch_bounds__(256) void k_tail2(const unsigned short* __restrict__ ttp,
                                               const unsigned short* __restrict__ Wo1T,
                                               const unsigned short* __restrict__ Wo2T,
                                               float* __restrict__ out,
                                               const float* __restrict__ sb,
                                               const float* __restrict__ s2b,
                                               const float* __restrict__ sc) {
  int blk = blockIdx.x;   // 512
  int b = blk >> 7, i = blk & 127;
  __shared__ __align__(16) unsigned short As[16384];
  __shared__ __align__(16) unsigned short Bs[16384];
  int tid = threadIdx.x;
  int w = tid >> 6, lane = tid & 63, quad = lane >> 4, l16 = lane & 15;
  facc zf = {0.f, 0.f, 0.f, 0.f};
  facc a1[2][8];
#pragma unroll
  for (int a = 0; a < 2; a++)
#pragma unroll
    for (int bq = 0; bq < 8; bq++) a1[a][bq] = zf;
  for (int kc = 0; kc < 4; kc++) {
    if (kc) __syncthreads();
    {
      int r = tid >> 1, half = tid & 1;
      int hc = kc * 128 + r;
      const unsigned short* src = ttp + (((size_t)(b * 8 + (hc >> 6)) * 64 + (hc & 63)) * 128 + i) * 128 + half * 64;
#pragma unroll
      for (int q = 0; q < 8; q++) {
        uint4 v = *(const uint4*)(src + q * 8);
        unsigned short* pv = (unsigned short*)&v;
#pragma unroll
        for (int e = 0; e < 8; e++) {
          int l = half * 64 + q * 8 + e;
          As[l * 128 + (((r >> 3) ^ (l & 15)) << 3) + (r & 7)] = pv[e];
        }
      }
      const unsigned short* sB = Wo1T + (size_t)r * 512 + kc * 128 + half * 64;
#pragma unroll
      for (int q = 0; q < 8; q++) {
        int c8 = half * 8 + q;
        *(uint4*)&Bs[r * 128 + ((c8 ^ (r & 15)) << 3)] = *(const uint4*)(sB + q * 8);
      }
    }
    __syncthreads();
#pragma unroll
    for (int k0 = 0; k0 < 4; k0++) {
      bfrag av[2];
#pragma unroll
      for (int it = 0; it < 2; it++) {
        int row = (w + it * 4) * 16 + l16;
        av[it] = *(const bfrag*)&As[row * 128 + (((k0 * 4 + quad) ^ l16) << 3)];
      }
#pragma unroll
      for (int nt = 0; nt < 8; nt++) {
        int row = nt * 16 + l16;
        bfrag bv = *(const bfrag*)&Bs[row * 128 + (((k0 * 4 + quad) ^ l16) << 3)];
        a1[0][nt] = __builtin_amdgcn_mfma_f32_16x16x32_bf16(av[0], bv, a1[0][nt], 0, 0, 0);
        a1[1][nt] = __builtin_amdgcn_mfma_f32_16x16x32_bf16(av[1], bv, a1[1][nt], 0, 0, 0);
      }
    }
  }
  float S = sb[b * 128 + i], S2 = s2b[b * 128 + i];
  float mean = S * (1.f / 65536.f);
  float var = S2 * (1.f / 65536.f) - mean * mean;
  float rs = rsqrtf(var + 1e-5f);
  __syncthreads();
#pragma unroll
  for (int it = 0; it < 2; it++)
#pragma unroll
    for (int nt = 0; nt < 8; nt++) {
      int n1 = nt * 16 + l16;
      float scn = sc[n1];
#pragma unroll
      for (int rr = 0; rr < 4; rr++) {
        int l = (w + it * 4) * 16 + quad * 4 + rr;
        float val = (a1[it][nt][rr] - mean * scn) * rs;
        As[l * 128 + (((n1 >> 3) ^ (l & 15)) << 3) + (n1 & 7)] = bf16r(gelu_f(val));
      }
    }
  {
    int r = tid >> 1, half = tid & 1;
    const unsigned short* sB = Wo2T + (size_t)r * 128 + half * 64;
#pragma unroll
    for (int q = 0; q < 8; q++) {
      int c8 = half * 8 + q;
      *(uint4*)&Bs[r * 128 + ((c8 ^ (r & 15)) << 3)] = *(const uint4*)(sB + q * 8);
    }
  }
  __syncthreads();
  facc a2[2][8];
#pragma unroll
  for (int a = 0; a < 2; a++)
#pragma unroll
    for (int bq = 0; bq < 8; bq++) a2[a][bq] = zf;
#pragma unroll
  for (int k0 = 0; k0 < 4; k0++) {
    bfrag av[2];
#pragma unroll
    for (int it = 0; it < 2; it++) {
      int row = (w + it * 4) * 16 + l16;
      av[it] = *(const bfrag*)&As[row * 128 + (((k0 * 4 + quad) ^ l16) << 3)];
    }
#pragma unroll
    for (int nt = 0; nt < 8; nt++) {
      int row = nt * 16 + l16;
      bfrag bv = *(const bfrag*)&Bs[row * 128 + (((k0 * 4 + quad) ^ l16) << 3)];
      a2[0][nt] = __builtin_amdgcn_mfma_f32_16x16x32_bf16(av[0], bv, a2[0][nt], 0, 0, 0);
      a2[1][nt] = __builtin_amdgcn_mfma_f32_16x16x32_bf16(av[1], bv, a2[1][nt], 0, 0, 0);
    }
  }
#pragma unroll
  for (int it = 0; it < 2; it++)
#pragma unroll
    for (int nt = 0; nt < 8; nt++) {
      int n2 = nt * 16 + l16;
#pragma unroll
      for (int rr = 0; rr < 4; rr++) {
        int l = (w + it * 4) * 16 + quad * 4 + rr;
        out[((size_t)(b * 16384 + i * 128 + l)) * 128 + n2] = a2[it][nt][rr];
      }
    }
}

extern "C" void kernel_launch(void* const* d_in, const int* in_sizes, int n_in,
                              void* d_out, int out_size, void* d_ws, size_t ws_size,
                              hipStream_t stream) {
  const float* u = (const float*)d_in[0];
  const float* pos_x = (const float*)d_in[1];
  const float* pos_y = (const float*)d_in[2];
  const float* ln_g = (const float*)d_in[3];
  const float* ln_b = (const float*)d_in[4];
  const float* Wv = (const float*)d_in[5];
  const float* Win = (const float*)d_in[6];
  const float* px_Win = (const float*)d_in[7];
  const float* px_g = (const float*)d_in[8];
  const float* px_b = (const float*)d_in[9];
  const float* px_W1 = (const float*)d_in[10];
  const float* px_b1 = (const float*)d_in[11];
  const float* px_W2 = (const float*)d_in[12];
  const float* px_b2 = (const float*)d_in[13];
  const float* py_Win = (const float*)d_in[14];
  const float* py_g = (const float*)d_in[15];
  const float* py_b = (const float*)d_in[16];
  const float* py_W1 = (const float*)d_in[17];
  const float* py_b1 = (const float*)d_in[18];
  const float* py_W2 = (const float*)d_in[19];
  const float* py_b2 = (const float*)d_in[20];
  const float* Wqk_x = (const float*)d_in[21];
  const float* Wqk_y = (const float*)d_in[22];
  const float* Wo1 = (const float*)d_in[23];
  const float* Wo2 = (const float*)d_in[24];
  float* out = (float*)d_out;

  const size_t NEED = 41723008;  // floats (~167 MB); harness ws is 256 MiB
  if (ws_size < NEED * sizeof(float)) return;
  float* ws = (float*)d_ws;
  unsigned short* un_bf = (unsigned short*)ws;               // [65536][128]
  unsigned short* vT    = (unsigned short*)(ws + 4194304);   // [512][65536]
  unsigned short* ttp   = (unsigned short*)(ws + 20971520);  // [32][64][128][128]
  float* small = ws + 37748736;
  float* mun_x = small;                 // 65536
  float* mun_y = small + 65536;         // 65536
  float* Wcx   = small + 131072;        // 16384
  float* Wcy   = small + 147456;        // 16384
  float* ux    = small + 163840;        // 32768
  float* uy    = small + 196608;        // 32768
  float* qkx   = small + 229376;        // 1572864
  float* qky   = small + 1802240;       // 1572864
  unsigned short* kx_bf = (unsigned short*)(small + 3375104);  // 524288 el
  unsigned short* ky_bf = (unsigned short*)(small + 3637248);  // 524288 el
  unsigned short* WvT   = (unsigned short*)(small + 3899392);  // 65536 el
  unsigned short* Wo1T  = (unsigned short*)(small + 3932160);  // 65536 el
  unsigned short* Wo2T  = (unsigned short*)(small + 3964928);  // 16384 el
  float* sbuf  = small + 3973120;       // 512
  float* s2buf = small + 3973632;       // 512
  float* scol  = small + 3974144;       // 128

  hipMemsetAsync(sbuf, 0, 1024 * sizeof(float), stream);

  // Phase A (6 dispatches)
  k_ln<<<ROWS, 128, 0, stream>>>(u, ln_g, ln_b, un_bf);
  k_means<<<1024, 128, 0, stream>>>(un_bf, mun_x, mun_y);
  k_wprep<<<585, 256, 0, stream>>>(Wv, Wo1, Wo2, Win, px_Win, py_Win,
                                   WvT, Wo1T, Wo2T, Wcx, Wcy, scol);
  k_pool2<<<dim3(512, 2), 128, 0, stream>>>(mun_x, mun_y, Wcx, Wcy, px_g, py_g, px_b, py_b,
                                            px_W1, py_W1, px_b1, py_b1, px_W2, py_W2,
                                            px_b2, py_b2, ux, uy);
  k_gemmz<<<dim3(48, 8, 2), 256, 0, stream>>>(ux, Wqk_x, qkx, uy, Wqk_y, qky,
                                              64, 64, 3072, 3072);
  k_qkt3<<<dim3(2, 2, 64), 256, 0, stream>>>(qkx, qky, pos_x, pos_y, kx_bf, ky_bf);

  // Phase B (3 dispatches)
  k_vt<<<512, 256, 0, stream>>>(WvT, un_bf, vT);
  k_fuse12<<<2048, 256, 0, stream>>>(kx_bf, ky_bf, vT, ttp, sbuf, s2buf);
  k_tail2<<<512, 256, 0, stream>>>(ttp, Wo1T, Wo2T, out, sbuf, s2buf, scol);
}